// Round 15
// baseline (536.574 us; speedup 1.0000x reference)
//
#include <hip/hip_runtime.h>
#include <stdint.h>

#define NROWS 8192
#define KDIM  1024
#define CAP   512
#define NEGBIG (-9.0e15f)
#define EMIT_THR 20.0f
#define SURV_THR 13.5f
#define MAXS  128

typedef __attribute__((ext_vector_type(8))) __bf16 bf16x8;
typedef __attribute__((ext_vector_type(4))) float f32x4;
typedef __attribute__((ext_vector_type(4))) unsigned short us4;
typedef __attribute__((ext_vector_type(4))) int i32x4;
typedef __attribute__((ext_vector_type(2))) long i64x2;
typedef __attribute__((ext_vector_type(16))) unsigned char u8x16;
typedef unsigned short u16;
typedef unsigned char u8;

__device__ __forceinline__ u16 f2bf(float f) {
  unsigned u = __float_as_uint(f);
  u += 0x7fffu + ((u >> 16) & 1u);
  return (u16)(u >> 16);
}
__device__ __forceinline__ float bf2f(u16 h) {
  return __uint_as_float(((unsigned)h) << 16);
}

// fp8 e4m3fn encode (RNE, saturate to 448)
__device__ __forceinline__ u8 f2fp8(float f) {
  uint32_t u = __float_as_uint(f);
  uint32_t s = (u >> 24) & 0x80u;
  int e = (int)((u >> 23) & 0xffu) - 127;
  uint32_t m = u & 0x7fffffu;
  if (e > 8 || (e == 8 && m > 0x600000u)) return (u8)(s | 0x7eu);
  if (e >= -6) {
    uint32_t mant = m >> 20;
    uint32_t rem = m & 0xfffffu;
    if (rem > 0x80000u || (rem == 0x80000u && (mant & 1u))) mant++;
    uint32_t ee = (uint32_t)(e + 7);
    if (mant == 8u) { mant = 0u; ee++; }
    if (ee >= 16u) return (u8)(s | 0x7eu);
    return (u8)(s | (ee << 3) | mant);
  }
  if (e < -10) return (u8)s;
  float af = fabsf(f);
  int q = (int)(af * 512.0f + 0.5f);
  if (q > 8) q = 8;
  return (u8)(s | (uint32_t)q);
}

__device__ __forceinline__ void glds16(const void* g, const char* lds) {
  __builtin_amdgcn_global_load_lds(
      (const __attribute__((address_space(1))) unsigned int*)(uintptr_t)g,
      (__attribute__((address_space(3))) unsigned int*)(uintptr_t)lds, 16, 0, 0);
}

__device__ __forceinline__ f32x4 mfma16(bf16x8 a, bf16x8 b, f32x4 c) {
  return __builtin_amdgcn_mfma_f32_16x16x32_bf16(a, b, c, 0, 0, 0);
}
__device__ __forceinline__ f32x4 mfma8(long a, long b, f32x4 c) {
  return __builtin_amdgcn_mfma_f32_16x16x32_fp8_fp8(a, b, c, 0, 0, 0);
}

// ---------------------------------------------------------------------------
// Pre-GEMM (R4-proven): C[128x128] = A@B^T, split-3 (NSPLIT=3) or 1-pass.
// ---------------------------------------------------------------------------
template<int NSPLIT, bool SPLITOUT>
__global__ __launch_bounds__(512, 1) void gemm_kernel(
    const u16* __restrict__ ah, const u16* __restrict__ al,
    const u16* __restrict__ bh, const u16* __restrict__ bl,
    const float* __restrict__ bias, u16* __restrict__ ch, u16* __restrict__ cl)
{
  extern __shared__ char smem[];
  constexpr int BUFS = (NSPLIT == 3) ? 65536 : 32768;
  constexpr int AHO = 0, ALO = 16384;
  constexpr int BHO = (NSPLIT == 3) ? 32768 : 16384;
  constexpr int BLO = 49152;
  constexpr int NT = KDIM / 64;

  const int tid = threadIdx.x, w = tid >> 6, lane = tid & 63;
  const int wr = w >> 2, wc = w & 3;
  const int bx = blockIdx.x, by = blockIdx.y;
  const int arow0 = bx * 128, bcol0 = by * 128;

  const int srow = w * 16 + (lane >> 3);
  const int scol = ((lane & 7) ^ (lane >> 3)) * 8;
  const size_t sgA = (size_t)(arow0 + srow) * KDIM + scol;
  const size_t sgB = (size_t)(bcol0 + srow) * KDIM + scol;
  const int ldsw = w * 2048;

  auto stg = [&](const u16* src, size_t sg, int kt, int ldsoff) {
    const u16* sp = src + sg + kt * 64;
    glds16(sp,            smem + ldsoff + ldsw);
    glds16(sp + 8 * KDIM, smem + ldsoff + ldsw + 1024);
  };

  const int fa = (wr * 64 + (lane & 15)) * 128;
  const int fb = (wc * 32 + (lane & 15)) * 128;
  const int kqx0 = (((lane >> 4)    ) ^ (lane & 7)) * 16;
  const int kqx1 = (((lane >> 4) + 4) ^ (lane & 7)) * 16;

  stg(ah, sgA, 0, AHO); stg(bh, sgB, 0, BHO);
  if constexpr (NSPLIT == 3) { stg(al, sgA, 0, ALO); stg(bl, sgB, 0, BLO); }
  else { stg(ah, sgA, 1, AHO + BUFS); stg(bh, sgB, 1, BHO + BUFS); }

  f32x4 acc[4][2];
  #pragma unroll
  for (int m = 0; m < 4; ++m) {
    acc[m][0] = f32x4{0.f, 0.f, 0.f, 0.f};
    acc[m][1] = f32x4{0.f, 0.f, 0.f, 0.f};
  }

  for (int t = 0; t < NT; ++t) {
    const int bo  = (t & 1) * BUFS;
    const int bo2 = ((t + 1) & 1) * BUFS;

    if (NSPLIT == 1 && t == NT - 1) asm volatile("s_waitcnt vmcnt(0)" ::: "memory");
    else                            asm volatile("s_waitcnt vmcnt(4)" ::: "memory");
    __builtin_amdgcn_s_barrier();
    __builtin_amdgcn_sched_barrier(0);

    if (NSPLIT == 3 && t + 1 < NT) {
      stg(ah, sgA, t + 1, AHO + bo2);
      stg(bh, sgB, t + 1, BHO + bo2);
    }

    bf16x8 a0[4][2], b0[2][2];
    #pragma unroll
    for (int m = 0; m < 4; ++m) {
      a0[m][0] = *(const bf16x8*)(smem + AHO + bo + fa + m * 2048 + kqx0);
      a0[m][1] = *(const bf16x8*)(smem + AHO + bo + fa + m * 2048 + kqx1);
    }
    #pragma unroll
    for (int n = 0; n < 2; ++n) {
      b0[n][0] = *(const bf16x8*)(smem + BHO + bo + fb + n * 2048 + kqx0);
      b0[n][1] = *(const bf16x8*)(smem + BHO + bo + fb + n * 2048 + kqx1);
    }
    __builtin_amdgcn_s_setprio(1);
    #pragma unroll
    for (int kq = 0; kq < 2; ++kq)
      #pragma unroll
      for (int m = 0; m < 4; ++m)
        #pragma unroll
        for (int n = 0; n < 2; ++n)
          acc[m][n] = mfma16(a0[m][kq], b0[n][kq], acc[m][n]);
    __builtin_amdgcn_s_setprio(0);
    asm volatile("s_waitcnt lgkmcnt(0)" ::: "memory");

    if constexpr (NSPLIT == 3) {
      if (t + 1 < NT) asm volatile("s_waitcnt vmcnt(4)" ::: "memory");
      else            asm volatile("s_waitcnt vmcnt(0)" ::: "memory");
      __builtin_amdgcn_s_barrier();
      __builtin_amdgcn_sched_barrier(0);

      if (t + 1 < NT) {
        stg(al, sgA, t + 1, ALO + bo2);
        stg(bl, sgB, t + 1, BLO + bo2);
      }
      bf16x8 a1[4][2], b1[2][2];
      #pragma unroll
      for (int m = 0; m < 4; ++m) {
        a1[m][0] = *(const bf16x8*)(smem + ALO + bo + fa + m * 2048 + kqx0);
        a1[m][1] = *(const bf16x8*)(smem + ALO + bo + fa + m * 2048 + kqx1);
      }
      #pragma unroll
      for (int n = 0; n < 2; ++n) {
        b1[n][0] = *(const bf16x8*)(smem + BLO + bo + fb + n * 2048 + kqx0);
        b1[n][1] = *(const bf16x8*)(smem + BLO + bo + fb + n * 2048 + kqx1);
      }
      __builtin_amdgcn_s_setprio(1);
      #pragma unroll
      for (int kq = 0; kq < 2; ++kq)
        #pragma unroll
        for (int m = 0; m < 4; ++m)
          #pragma unroll
          for (int n = 0; n < 2; ++n)
            acc[m][n] = mfma16(a1[m][kq], b0[n][kq], acc[m][n]);
      #pragma unroll
      for (int kq = 0; kq < 2; ++kq)
        #pragma unroll
        for (int m = 0; m < 4; ++m)
          #pragma unroll
          for (int n = 0; n < 2; ++n)
            acc[m][n] = mfma16(a0[m][kq], b1[n][kq], acc[m][n]);
      __builtin_amdgcn_s_setprio(0);
      asm volatile("s_waitcnt lgkmcnt(0)" ::: "memory");
    } else {
      __builtin_amdgcn_s_barrier();
      if (t + 2 < NT) {
        stg(ah, sgA, t + 2, AHO + bo);
        stg(bh, sgB, t + 2, BHO + bo);
      }
    }
  }

  const int l15 = lane & 15, g4 = (lane >> 4) << 2;
  const int colb = bcol0 + wc * 32 + l15;
  const float bi0 = bias[colb], bi1 = bias[colb + 16];
  #pragma unroll
  for (int m = 0; m < 4; ++m) {
    #pragma unroll
    for (int j = 0; j < 4; ++j) {
      const int row = arow0 + wr * 64 + m * 16 + g4 + j;
      float v0 = acc[m][0][j] + bi0, v1 = acc[m][1][j] + bi1;
      u16 h0 = f2bf(v0), h1 = f2bf(v1);
      ch[(size_t)row * KDIM + colb] = h0;
      ch[(size_t)row * KDIM + colb + 16] = h1;
      if constexpr (SPLITOUT) {
        cl[(size_t)row * KDIM + colb] = f2bf(v0 - bf2f(h0));
        cl[(size_t)row * KDIM + colb + 16] = f2bf(v1 - bf2f(h1));
      }
    }
  }
}

// ---------------------------------------------------------------------------
// Quantize bf16-hi -> fp8 e4m3, frag-pair-permuted layout (R13-proven):
// 16B cell c of megatile mt: bytes j -> k = (2*(c>>2)+(j>=8))*32 + (c&3)*8 + j%8.
// ---------------------------------------------------------------------------
__global__ __launch_bounds__(256) void quant_kernel(
    const u16* __restrict__ src, u8* __restrict__ dst)
{
  const int id = blockIdx.x * 256 + threadIdx.x;   // one 16B cell
  const int row = id >> 6, mtc = id & 63;
  const int mt = mtc >> 3, c = mtc & 7;
  const int k0 = mt * 128 + (c >> 2) * 64 + (c & 3) * 8;
  const u16* s0 = src + (size_t)row * KDIM + k0;
  u8x16 o;
  #pragma unroll
  for (int j = 0; j < 8; ++j) o[j] = f2fp8(bf2f(s0[j]));
  #pragma unroll
  for (int j = 0; j < 8; ++j) o[8 + j] = f2fp8(bf2f(s0[32 + j]));
  *(u8x16*)(dst + (size_t)id * 16) = o;
}

// ---------------------------------------------------------------------------
// Scores sweep R15: 128x128 fp8 tile, BK=64, 256-thread wgs (4 waves, 2x2),
// 32KB LDS -> FOUR independent wgs per CU (R14 proved independence is the
// lever; this doubles it) + wave tile 64x64 -> 8 b128 reads per 32 MFMA
// (0.25/MFMA vs R14's 0.375). Grid 1024 = exactly 4/CU, zero tail.
// LDS row-pair layout (fixes 64B-row conflicts): LDS row R (0..63) packs
// global rows R and R+64; logical cell q = h*4 + hi4 (h = row>=64), phys
// p = q ^ (R&7). Read: 2 lanes/bank (free). Write: glds-linear dest, source
// pre-swizzled with the same involution.
// Schedule/vmcnt = R14 verbatim: counted vmcnt(4), lookahead 2, 2 barriers.
// ---------------------------------------------------------------------------
__global__ __launch_bounds__(256, 4) void scores_kernel(
    const u8* __restrict__ fq, const u8* __restrict__ gq,
    const uint32_t* __restrict__ adjb, uint32_t* __restrict__ cand,
    int* __restrict__ cnts, int* rowmax)
{
  extern __shared__ char smem[];
  constexpr int NT = 64;                 // 4 key-tiles x 16 BK-64 steps

  const int tid = threadIdx.x, w = tid >> 6, lane = tid & 63;
  const int wr = w >> 1, wc = w & 1;
  const int l15 = lane & 15, g4 = (lane >> 4) << 2, hi4 = lane >> 4;

  // 1024 wgs: XCD hosts 8 slabs (128 rows) x 16 siblings
  const int xcd = blockIdx.x & 7, idx = blockIdx.x >> 3;
  const int slab = xcd * 8 + (idx & 7);
  const int sub  = idx >> 3;             // 0..15 -> key-tiles {sub+16i, i<4}
  const int arow0 = slab * 128;

  // ---- staging: 2 cells/thread/matrix; cell d -> LDS row R=d>>3, phys p=d&7,
  //      logical q = p^(R&7) -> global row R+64*(q>>2), hi4-cell q&3
  int sgrow[2], scc[2];
  #pragma unroll
  for (int i = 0; i < 2; ++i) {
    const int d = i * 256 + tid;
    const int R = d >> 3, q = (d & 7) ^ (R & 7);
    sgrow[i] = R + 64 * (q >> 2);
    scc[i]   = q & 3;
  }

  auto stageA = [&](int T) {
    const int tk = T & 15;
    const int koff = (tk >> 1) * 128 + (tk & 1) * 64;
    char* dbase = smem + (T & 1) * 16384 + w * 1024;
    glds16(fq + (size_t)(arow0 + sgrow[0]) * KDIM + koff + scc[0] * 16, dbase);
    glds16(fq + (size_t)(arow0 + sgrow[1]) * KDIM + koff + scc[1] * 16, dbase + 4096);
  };
  auto stageB = [&](int T) {
    const int tk = T & 15;
    const int koff = (tk >> 1) * 128 + (tk & 1) * 64;
    const size_t kb = (size_t)(sub + 16 * (T >> 4)) * 128;
    char* dbase = smem + (T & 1) * 16384 + 8192 + w * 1024;
    glds16(gq + (kb + sgrow[0]) * KDIM + koff + scc[0] * 16, dbase);
    glds16(gq + (kb + sgrow[1]) * KDIM + koff + scc[1] * 16, dbase + 4096);
  };

  // ---- fragment read offsets: q = half*4 + hi4, phys = q ^ (R&7), R&7=l15&7
  const int kxa = ((wr * 4 + hi4) ^ (l15 & 7)) * 16;
  const int kxb = ((wc * 4 + hi4) ^ (l15 & 7)) * 16;

  f32x4 acc[4][4];
  #pragma unroll
  for (int m = 0; m < 4; ++m)
    #pragma unroll
    for (int n = 0; n < 4; ++n) acc[m][n] = f32x4{0.f, 0.f, 0.f, 0.f};

  const unsigned long long lmask = (1ull << lane) - 1ull;
  const unsigned long long gm = 0xFFFFull << (lane & 48);

  // ---- prologue: stage tiles 0,1 (8 glds/thread outstanding)
  stageA(0); stageB(0);
  stageA(1); stageB(1);

  i64x2 a[4], b[4];

  for (int T = 0; T < NT; ++T) {
    // counted: retires stage(T) exactly; stage(T+1) stays in flight
    if (T == NT - 1) asm volatile("s_waitcnt vmcnt(0)" ::: "memory");
    else             asm volatile("s_waitcnt vmcnt(4)" ::: "memory");
    __builtin_amdgcn_s_barrier();

    const char* sb = smem + (T & 1) * 16384;
    #pragma unroll
    for (int m = 0; m < 4; ++m)
      a[m] = *(const i64x2*)(sb + (m * 16 + l15) * 128 + kxa);
    #pragma unroll
    for (int n = 0; n < 4; ++n)
      b[n] = *(const i64x2*)(sb + 8192 + (n * 16 + l15) * 128 + kxb);

    __builtin_amdgcn_s_setprio(1);
    #pragma unroll
    for (int kh = 0; kh < 2; ++kh)
      #pragma unroll
      for (int m = 0; m < 4; ++m)
        #pragma unroll
        for (int n = 0; n < 4; ++n)
          acc[m][n] = mfma8(a[m][kh], b[n][kh], acc[m][n]);
    __builtin_amdgcn_s_setprio(0);
    // own ds_reads drained -> after the barrier, buf[T&1] is overwritable
    asm volatile("s_waitcnt lgkmcnt(0)" ::: "memory");
    __builtin_amdgcn_s_barrier();

    if (T + 2 < NT) { stageA(T + 2); stageB(T + 2); }

    // ===== key-tile epilogue (every 16 tiles), latency-overlapped =====
    if ((T & 15) == 15) {
      const int kcol0 = (sub + 16 * (T >> 4)) * 128;
      const int keyb = kcol0 + wc * 64 + l15;
      #pragma unroll
      for (int mc = 0; mc < 2; ++mc) {
        // -- phase A: batch-prefetch adjacency words + rowmax
        uint32_t A0[2][4], A1[2][4]; float RX[2][4]; int ROW[2][4];
        #pragma unroll
        for (int mm = 0; mm < 2; ++mm)
          #pragma unroll
          for (int j = 0; j < 4; ++j) {
            const int m = mc * 2 + mm;
            const int row = arow0 + wr * 64 + m * 16 + g4 + j;
            ROW[mm][j] = row;
            const uint32_t* ap = adjb + (size_t)row * (NROWS / 32) + (kcol0 >> 5) + wc * 2;
            A0[mm][j] = ap[0];
            A1[mm][j] = ap[1];
            RX[mm][j] = __int_as_float(rowmax[row]);   // stale-tolerant
          }
        // -- phase B: mask/reduce; fire atomicMax; issue atomicAdds
        float SV[2][4][4]; float TH[2][4]; int BS[2][4];
        #pragma unroll
        for (int mm = 0; mm < 2; ++mm)
          #pragma unroll
          for (int j = 0; j < 4; ++j) {
            const int m = mc * 2 + mm;
            float rm = NEGBIG;
            #pragma unroll
            for (int n = 0; n < 4; ++n) {
              float v = fmaxf(acc[m][n][j], 0.f);
              uint32_t bit = ((n < 2 ? A0[mm][j] : A1[mm][j]) >> ((n & 1) * 16 + l15)) & 1u;
              float s = bit ? v : NEGBIG;
              SV[mm][j][n] = s;
              rm = fmaxf(rm, s);
            }
            rm = fmaxf(rm, __shfl_xor(rm, 1));
            rm = fmaxf(rm, __shfl_xor(rm, 2));
            rm = fmaxf(rm, __shfl_xor(rm, 4));
            rm = fmaxf(rm, __shfl_xor(rm, 8));
            const float mr = fmaxf(rm, RX[mm][j]);
            if (l15 == 0 && rm > RX[mm][j])
              atomicMax(rowmax + ROW[mm][j], __float_as_int(rm));
            TH[mm][j] = mr - EMIT_THR;
            int tot = 0;
            #pragma unroll
            for (int n = 0; n < 4; ++n)
              tot += __popcll(__ballot(SV[mm][j][n] > TH[mm][j]) & gm);
            BS[mm][j] = 0;
            if (l15 == 0 && tot > 0)
              BS[mm][j] = atomicAdd(cnts + ROW[mm][j], tot);
          }
        // -- phase C: re-ballot, place, store
        #pragma unroll
        for (int mm = 0; mm < 2; ++mm)
          #pragma unroll
          for (int j = 0; j < 4; ++j) {
            int base = __shfl(BS[mm][j], lane & 48);
            int pref = 0;
            #pragma unroll
            for (int n = 0; n < 4; ++n) {
              unsigned long long mk = __ballot(SV[mm][j][n] > TH[mm][j]);
              const int p = base + pref + __popcll(mk & gm & lmask);
              if ((SV[mm][j][n] > TH[mm][j]) && p < CAP)
                cand[(size_t)ROW[mm][j] * CAP + p] =
                    ((uint32_t)f2bf(SV[mm][j][n]) << 16) | (uint32_t)(keyb + n * 16);
              pref += __popcll(mk & gm);
            }
          }
      }
      #pragma unroll
      for (int m = 0; m < 4; ++m)
        #pragma unroll
        for (int n = 0; n < 4; ++n) acc[m][n] = f32x4{0.f, 0.f, 0.f, 0.f};
    }
  }
}

// ---------------------------------------------------------------------------
// adj (int32 0/1, 268 MB) -> bitmask (8 MB). BW-bound single pass.
// ---------------------------------------------------------------------------
__global__ __launch_bounds__(256) void adjpack_kernel(
    const int* __restrict__ adj, uint32_t* __restrict__ adjb)
{
  size_t w = (size_t)blockIdx.x * 256 + threadIdx.x;
  const int* src = adj + (w << 5);
  uint32_t m = 0;
  #pragma unroll
  for (int j = 0; j < 8; ++j) {
    i32x4 v = *(const i32x4*)(src + j * 4);
    m |= (v[0] > 0 ? 1u : 0u) << (j * 4)
       | (v[1] > 0 ? 1u : 0u) << (j * 4 + 1)
       | (v[2] > 0 ? 1u : 0u) << (j * 4 + 2)
       | (v[3] > 0 ? 1u : 0u) << (j * 4 + 3);
  }
  adjb[w] = m;
}

// ---------------------------------------------------------------------------
// Finalize: survivors (within SURV_THR of approx max) rescored exactly in
// fp32 from (fh+fl, gh+gl); tail stays approx in the denominator only.
// ---------------------------------------------------------------------------
__global__ __launch_bounds__(256) void finalize_kernel(
    const uint32_t* __restrict__ cand, const int* __restrict__ cnts,
    const u16* __restrict__ fh, const u16* __restrict__ fl,
    const u16* __restrict__ gh, const u16* __restrict__ gl,
    const u16* __restrict__ vh, float* __restrict__ out)
{
  const int row = blockIdx.x, tid = threadIdx.x, wv = tid >> 6, lane = tid & 63;
  __shared__ float sS[CAP];
  __shared__ int sK[CAP];
  __shared__ float sF[KDIM];
  __shared__ float sEx[MAXS];
  __shared__ int sKs[MAXS];
  __shared__ float red[4];
  __shared__ int nsig;
  int cnt = cnts[row]; cnt = cnt < CAP ? cnt : CAP;
  const int col = tid * 4;
  if (cnt <= 0) {
    f32x4 z = {0.f, 0.f, 0.f, 0.f};
    *(f32x4*)(out + (size_t)row * KDIM + col) = z;
    return;
  }
  if (tid == 0) nsig = 0;
  {
    us4 h = *(const us4*)(fh + (size_t)row * KDIM + col);
    us4 l = *(const us4*)(fl + (size_t)row * KDIM + col);
    #pragma unroll
    for (int j = 0; j < 4; ++j) sF[col + j] = bf2f(h[j]) + bf2f(l[j]);
  }
  for (int i = tid; i < cnt; i += 256) {
    uint32_t pk = cand[(size_t)row * CAP + i];
    sS[i] = bf2f((u16)(pk >> 16));
    sK[i] = (int)(pk & 0xFFFFu);
  }
  __syncthreads();
  float lm = NEGBIG;
  for (int i = tid; i < cnt; i += 256) lm = fmaxf(lm, sS[i]);
  #pragma unroll
  for (int d = 1; d < 64; d <<= 1) lm = fmaxf(lm, __shfl_xor(lm, d));
  if ((tid & 63) == 0) red[tid >> 6] = lm;
  __syncthreads();
  const float am = fmaxf(fmaxf(red[0], red[1]), fmaxf(red[2], red[3]));
  __syncthreads();
  for (int i = tid; i < cnt; i += 256) {
    if (sS[i] > am - SURV_THR) {
      int p = atomicAdd(&nsig, 1);
      if (p < MAXS) { sKs[p] = sK[i]; sS[i] = NEGBIG; }
    }
  }
  __syncthreads();
  const int ns = nsig < MAXS ? nsig : MAXS;
  for (int si = wv; si < ns; si += 4) {
    const int key = sKs[si];
    const u16* grh = gh + (size_t)key * KDIM + lane * 16;
    const u16* grl = gl + (size_t)key * KDIM + lane * 16;
    float d = 0.f;
    #pragma unroll
    for (int u = 0; u < 4; ++u) {
      us4 h = *(const us4*)(grh + u * 4);
      us4 l = *(const us4*)(grl + u * 4);
      #pragma unroll
      for (int j = 0; j < 4; ++j)
        d += (bf2f(h[j]) + bf2f(l[j])) * sF[lane * 16 + u * 4 + j];
    }
    #pragma unroll
    for (int dd = 1; dd < 64; dd <<= 1) d += __shfl_xor(d, dd);
    if (lane == 0) sEx[si] = fmaxf(d, 0.f);
  }
  __syncthreads();
  float em = NEGBIG;
  for (int i = tid; i < ns; i += 256) em = fmaxf(em, sEx[i]);
  #pragma unroll
  for (int d = 1; d < 64; d <<= 1) em = fmaxf(em, __shfl_xor(em, d));
  if ((tid & 63) == 0) red[tid >> 6] = em;
  __syncthreads();
  const float m = fmaxf(fmaxf(red[0], red[1]), fmaxf(red[2], red[3]));
  __syncthreads();
  float ls = 0.f;
  for (int i = tid; i < cnt; i += 256) {
    float s = sS[i];
    if (s > NEGBIG * 0.5f) ls += __expf(s - m);
  }
  for (int i = tid; i < ns; i += 256) ls += __expf(sEx[i] - m);
  #pragma unroll
  for (int d = 1; d < 64; d <<= 1) ls += __shfl_xor(ls, d);
  if ((tid & 63) == 0) red[tid >> 6] = ls;
  __syncthreads();
  const float inv = 1.f / (red[0] + red[1] + red[2] + red[3]);
  float a0 = 0.f, a1 = 0.f, a2 = 0.f, a3 = 0.f;
  const u16* vbase = vh + col;
  for (int i = 0; i < ns; ++i) {
    const float wt = __expf(sEx[i] - m) * inv;
    us4 vv = *(const us4*)(vbase + (size_t)sKs[i] * KDIM);
    a0 += wt * bf2f(vv[0]); a1 += wt * bf2f(vv[1]);
    a2 += wt * bf2f(vv[2]); a3 += wt * bf2f(vv[3]);
  }
  f32x4 o = {a0, a1, a2, a3};
  *(f32x4*)(out + (size_t)row * KDIM + col) = o;
}

// ---------------------------------------------------------------------------
// Transpose + hi/lo split of a [K][N] fp32 weight into [N][K] bf16 pair.
// ---------------------------------------------------------------------------
__global__ __launch_bounds__(256) void wsplit_kernel(
    const float* __restrict__ W, u16* __restrict__ th, u16* __restrict__ tl)
{
  __shared__ float tile[32][33];
  const int bx = blockIdx.x, by = blockIdx.y;
  const int tx = threadIdx.x & 31, ty = threadIdx.x >> 5;
  #pragma unroll
  for (int i = 0; i < 4; ++i) {
    int ky = ty + i * 8;
    tile[ky][tx] = W[(size_t)(by * 32 + ky) * KDIM + bx * 32 + tx];
  }
  __syncthreads();
  #pragma unroll
  for (int i = 0; i < 4; ++i) {
    int ny = ty + i * 8;
    float v = tile[tx][ny];
    u16 h = f2bf(v);
    th[(size_t)(bx * 32 + ny) * KDIM + by * 32 + tx] = h;
    tl[(size_t)(bx * 32 + ny) * KDIM + by * 32 + tx] = f2bf(v - bf2f(h));
  }
}

__global__ __launch_bounds__(256) void xsplit_kernel(
    const float* __restrict__ x, u16* __restrict__ xh, u16* __restrict__ xl)
{
  size_t i = ((size_t)blockIdx.x * 256 + threadIdx.x) * 4;
  f32x4 v = *(const f32x4*)(x + i);
  us4 h, l;
  #pragma unroll
  for (int j = 0; j < 4; ++j) {
    h[j] = f2bf(v[j]);
    l[j] = f2bf(v[j] - bf2f(h[j]));
  }
  *(us4*)(xh + i) = h;
  *(us4*)(xl + i) = l;
}

__global__ void ws_report(float* out, size_t n, float v) {
  for (size_t i = (size_t)blockIdx.x * blockDim.x + threadIdx.x; i < n;
       i += (size_t)gridDim.x * blockDim.x) out[i] = v;
}

extern "C" void kernel_launch(void* const* d_in, const int* in_sizes, int n_in,
                              void* d_out, int out_size, void* d_ws, size_t ws_size,
                              hipStream_t stream) {
  (void)in_sizes; (void)n_in;
  const float* x   = (const float*)d_in[0];
  const int*   adj = (const int*)d_in[1];
  const float* Wf  = (const float*)d_in[2];
  const float* bf_ = (const float*)d_in[3];
  const float* Wg  = (const float*)d_in[4];
  const float* bg_ = (const float*)d_in[5];
  const float* W   = (const float*)d_in[6];
  const float* bW_ = (const float*)d_in[7];

  char* p = (char*)d_ws;
  const size_t ND2 = (size_t)NROWS * KDIM * 2;
  const size_t ND1 = (size_t)NROWS * KDIM;
  const size_t W2  = (size_t)KDIM * KDIM * 2;
  u16* xh = (u16*)p;  p += ND2;
  u16* xl = (u16*)p;  p += ND2;
  u16* fh = (u16*)p;  p += ND2;
  u16* fl = (u16*)p;  p += ND2;
  u16* gh = (u16*)p;  p += ND2;
  u16* gl = (u16*)p;  p += ND2;
  u16* vh = (u16*)p;  p += ND2;
  u16* wfh = (u16*)p; p += W2;
  u16* wfl = (u16*)p; p += W2;
  u16* wgh = (u16*)p; p += W2;
  u16* wgl = (u16*)p; p += W2;
  u16* wh  = (u16*)p; p += W2;
  u16* wl  = (u16*)p; p += W2;
  u8* fq = (u8*)p; p += ND1;
  u8* gq = (u8*)p; p += ND1;
  uint32_t* cand = (uint32_t*)p; p += (size_t)NROWS * CAP * 4;
  int* cnts   = (int*)p; p += (size_t)NROWS * 4;
  int* rowmax = (int*)p; p += (size_t)NROWS * 4;
  const size_t need = (size_t)(p - (char*)d_ws);
  if (ws_size < need) {
    ws_report<<<256, 256, 0, stream>>>((float*)d_out, (size_t)out_size, (float)ws_size);
    return;
  }
  uint32_t* adjb = (uint32_t*)xl;   // aliases xl after pre-GEMMs are done

  auto kf = gemm_kernel<3, true>;
  auto kv = gemm_kernel<1, false>;
  hipFuncSetAttribute((const void*)kf, hipFuncAttributeMaxDynamicSharedMemorySize, 131072);
  hipFuncSetAttribute((const void*)kv, hipFuncAttributeMaxDynamicSharedMemorySize, 65536);
  hipFuncSetAttribute((const void*)scores_kernel, hipFuncAttributeMaxDynamicSharedMemorySize, 32768);

  hipMemsetAsync(cnts, 0, (size_t)NROWS * 8, stream);   // cnts + rowmax (0 == 0.0f)
  wsplit_kernel<<<dim3(32, 32), 256, 0, stream>>>(Wf, wfh, wfl);
  wsplit_kernel<<<dim3(32, 32), 256, 0, stream>>>(Wg, wgh, wgl);
  wsplit_kernel<<<dim3(32, 32), 256, 0, stream>>>(W, wh, wl);
  xsplit_kernel<<<(NROWS * KDIM) / (256 * 4), 256, 0, stream>>>(x, xh, xl);

  // f = x@Wf + bf, g = x@Wg + bg (split-3, hi+lo out), v = x@W + bW (1 pass)
  kf<<<dim3(64, 8), 512, 131072, stream>>>(xh, xl, wfh, wfl, bf_, fh, fl);
  kf<<<dim3(64, 8), 512, 131072, stream>>>(xh, xl, wgh, wgl, bg_, gh, gl);
  kv<<<dim3(64, 8), 512, 65536, stream>>>(xh, xl, wh, wl, bW_, vh, nullptr);
  // fp8 quantize (frag-pair permuted) for the scores sweep
  quant_kernel<<<(NROWS * 64) / 256, 256, 0, stream>>>(fh, fq);
  quant_kernel<<<(NROWS * 64) / 256, 256, 0, stream>>>(gh, gq);
  adjpack_kernel<<<(NROWS * (NROWS / 32)) / 256, 256, 0, stream>>>(adj, adjb);
  // 4-wg/CU fp8 scores sweep + bounded candidate emission
  scores_kernel<<<dim3(1024), 256, 32768, stream>>>(fq, gq, adjb, cand, cnts, rowmax);
  // exact rescoring of survivors + softmax + v gather
  finalize_kernel<<<NROWS, 256, 0, stream>>>(cand, cnts, fh, fl, gh, gl, vh,
                                             (float*)d_out);
}

// Round 16
// 464.248 us; speedup vs baseline: 1.1558x; 1.1558x over previous
//
#include <hip/hip_runtime.h>
#include <stdint.h>

#define NROWS 8192
#define KDIM  1024
#define CAP   512
#define NEGBIG (-9.0e15f)
#define EMIT_THR 20.0f
#define SURV_THR 13.5f
#define MAXS  128

typedef __attribute__((ext_vector_type(8))) __bf16 bf16x8;
typedef __attribute__((ext_vector_type(4))) float f32x4;
typedef __attribute__((ext_vector_type(4))) unsigned short us4;
typedef __attribute__((ext_vector_type(4))) int i32x4;
typedef __attribute__((ext_vector_type(2))) long i64x2;
typedef __attribute__((ext_vector_type(16))) unsigned char u8x16;
typedef unsigned short u16;
typedef unsigned char u8;

__device__ __forceinline__ u16 f2bf(float f) {
  unsigned u = __float_as_uint(f);
  u += 0x7fffu + ((u >> 16) & 1u);
  return (u16)(u >> 16);
}
__device__ __forceinline__ float bf2f(u16 h) {
  return __uint_as_float(((unsigned)h) << 16);
}

// fp8 e4m3fn encode (RNE, saturate to 448)
__device__ __forceinline__ u8 f2fp8(float f) {
  uint32_t u = __float_as_uint(f);
  uint32_t s = (u >> 24) & 0x80u;
  int e = (int)((u >> 23) & 0xffu) - 127;
  uint32_t m = u & 0x7fffffu;
  if (e > 8 || (e == 8 && m > 0x600000u)) return (u8)(s | 0x7eu);
  if (e >= -6) {
    uint32_t mant = m >> 20;
    uint32_t rem = m & 0xfffffu;
    if (rem > 0x80000u || (rem == 0x80000u && (mant & 1u))) mant++;
    uint32_t ee = (uint32_t)(e + 7);
    if (mant == 8u) { mant = 0u; ee++; }
    if (ee >= 16u) return (u8)(s | 0x7eu);
    return (u8)(s | (ee << 3) | mant);
  }
  if (e < -10) return (u8)s;
  float af = fabsf(f);
  int q = (int)(af * 512.0f + 0.5f);
  if (q > 8) q = 8;
  return (u8)(s | (uint32_t)q);
}

__device__ __forceinline__ void glds16(const void* g, const char* lds) {
  __builtin_amdgcn_global_load_lds(
      (const __attribute__((address_space(1))) unsigned int*)(uintptr_t)g,
      (__attribute__((address_space(3))) unsigned int*)(uintptr_t)lds, 16, 0, 0);
}

__device__ __forceinline__ f32x4 mfma16(bf16x8 a, bf16x8 b, f32x4 c) {
  return __builtin_amdgcn_mfma_f32_16x16x32_bf16(a, b, c, 0, 0, 0);
}
__device__ __forceinline__ f32x4 mfma8(long a, long b, f32x4 c) {
  return __builtin_amdgcn_mfma_f32_16x16x32_fp8_fp8(a, b, c, 0, 0, 0);
}

// ---------------------------------------------------------------------------
// Pre-GEMM (R4-proven): C[128x128] = A@B^T, split-3 (NSPLIT=3) or 1-pass.
// ---------------------------------------------------------------------------
template<int NSPLIT, bool SPLITOUT>
__global__ __launch_bounds__(512, 1) void gemm_kernel(
    const u16* __restrict__ ah, const u16* __restrict__ al,
    const u16* __restrict__ bh, const u16* __restrict__ bl,
    const float* __restrict__ bias, u16* __restrict__ ch, u16* __restrict__ cl)
{
  extern __shared__ char smem[];
  constexpr int BUFS = (NSPLIT == 3) ? 65536 : 32768;
  constexpr int AHO = 0, ALO = 16384;
  constexpr int BHO = (NSPLIT == 3) ? 32768 : 16384;
  constexpr int BLO = 49152;
  constexpr int NT = KDIM / 64;

  const int tid = threadIdx.x, w = tid >> 6, lane = tid & 63;
  const int wr = w >> 2, wc = w & 3;
  const int bx = blockIdx.x, by = blockIdx.y;
  const int arow0 = bx * 128, bcol0 = by * 128;

  const int srow = w * 16 + (lane >> 3);
  const int scol = ((lane & 7) ^ (lane >> 3)) * 8;
  const size_t sgA = (size_t)(arow0 + srow) * KDIM + scol;
  const size_t sgB = (size_t)(bcol0 + srow) * KDIM + scol;
  const int ldsw = w * 2048;

  auto stg = [&](const u16* src, size_t sg, int kt, int ldsoff) {
    const u16* sp = src + sg + kt * 64;
    glds16(sp,            smem + ldsoff + ldsw);
    glds16(sp + 8 * KDIM, smem + ldsoff + ldsw + 1024);
  };

  const int fa = (wr * 64 + (lane & 15)) * 128;
  const int fb = (wc * 32 + (lane & 15)) * 128;
  const int kqx0 = (((lane >> 4)    ) ^ (lane & 7)) * 16;
  const int kqx1 = (((lane >> 4) + 4) ^ (lane & 7)) * 16;

  stg(ah, sgA, 0, AHO); stg(bh, sgB, 0, BHO);
  if constexpr (NSPLIT == 3) { stg(al, sgA, 0, ALO); stg(bl, sgB, 0, BLO); }
  else { stg(ah, sgA, 1, AHO + BUFS); stg(bh, sgB, 1, BHO + BUFS); }

  f32x4 acc[4][2];
  #pragma unroll
  for (int m = 0; m < 4; ++m) {
    acc[m][0] = f32x4{0.f, 0.f, 0.f, 0.f};
    acc[m][1] = f32x4{0.f, 0.f, 0.f, 0.f};
  }

  for (int t = 0; t < NT; ++t) {
    const int bo  = (t & 1) * BUFS;
    const int bo2 = ((t + 1) & 1) * BUFS;

    if (NSPLIT == 1 && t == NT - 1) asm volatile("s_waitcnt vmcnt(0)" ::: "memory");
    else                            asm volatile("s_waitcnt vmcnt(4)" ::: "memory");
    __builtin_amdgcn_s_barrier();
    __builtin_amdgcn_sched_barrier(0);

    if (NSPLIT == 3 && t + 1 < NT) {
      stg(ah, sgA, t + 1, AHO + bo2);
      stg(bh, sgB, t + 1, BHO + bo2);
    }

    bf16x8 a0[4][2], b0[2][2];
    #pragma unroll
    for (int m = 0; m < 4; ++m) {
      a0[m][0] = *(const bf16x8*)(smem + AHO + bo + fa + m * 2048 + kqx0);
      a0[m][1] = *(const bf16x8*)(smem + AHO + bo + fa + m * 2048 + kqx1);
    }
    #pragma unroll
    for (int n = 0; n < 2; ++n) {
      b0[n][0] = *(const bf16x8*)(smem + BHO + bo + fb + n * 2048 + kqx0);
      b0[n][1] = *(const bf16x8*)(smem + BHO + bo + fb + n * 2048 + kqx1);
    }
    __builtin_amdgcn_s_setprio(1);
    #pragma unroll
    for (int kq = 0; kq < 2; ++kq)
      #pragma unroll
      for (int m = 0; m < 4; ++m)
        #pragma unroll
        for (int n = 0; n < 2; ++n)
          acc[m][n] = mfma16(a0[m][kq], b0[n][kq], acc[m][n]);
    __builtin_amdgcn_s_setprio(0);
    asm volatile("s_waitcnt lgkmcnt(0)" ::: "memory");

    if constexpr (NSPLIT == 3) {
      if (t + 1 < NT) asm volatile("s_waitcnt vmcnt(4)" ::: "memory");
      else            asm volatile("s_waitcnt vmcnt(0)" ::: "memory");
      __builtin_amdgcn_s_barrier();
      __builtin_amdgcn_sched_barrier(0);

      if (t + 1 < NT) {
        stg(al, sgA, t + 1, ALO + bo2);
        stg(bl, sgB, t + 1, BLO + bo2);
      }
      bf16x8 a1[4][2], b1[2][2];
      #pragma unroll
      for (int m = 0; m < 4; ++m) {
        a1[m][0] = *(const bf16x8*)(smem + ALO + bo + fa + m * 2048 + kqx0);
        a1[m][1] = *(const bf16x8*)(smem + ALO + bo + fa + m * 2048 + kqx1);
      }
      #pragma unroll
      for (int n = 0; n < 2; ++n) {
        b1[n][0] = *(const bf16x8*)(smem + BLO + bo + fb + n * 2048 + kqx0);
        b1[n][1] = *(const bf16x8*)(smem + BLO + bo + fb + n * 2048 + kqx1);
      }
      __builtin_amdgcn_s_setprio(1);
      #pragma unroll
      for (int kq = 0; kq < 2; ++kq)
        #pragma unroll
        for (int m = 0; m < 4; ++m)
          #pragma unroll
          for (int n = 0; n < 2; ++n)
            acc[m][n] = mfma16(a1[m][kq], b0[n][kq], acc[m][n]);
      #pragma unroll
      for (int kq = 0; kq < 2; ++kq)
        #pragma unroll
        for (int m = 0; m < 4; ++m)
          #pragma unroll
          for (int n = 0; n < 2; ++n)
            acc[m][n] = mfma16(a0[m][kq], b1[n][kq], acc[m][n]);
      __builtin_amdgcn_s_setprio(0);
      asm volatile("s_waitcnt lgkmcnt(0)" ::: "memory");
    } else {
      __builtin_amdgcn_s_barrier();
      if (t + 2 < NT) {
        stg(ah, sgA, t + 2, AHO + bo);
        stg(bh, sgB, t + 2, BHO + bo);
      }
    }
  }

  const int l15 = lane & 15, g4 = (lane >> 4) << 2;
  const int colb = bcol0 + wc * 32 + l15;
  const float bi0 = bias[colb], bi1 = bias[colb + 16];
  #pragma unroll
  for (int m = 0; m < 4; ++m) {
    #pragma unroll
    for (int j = 0; j < 4; ++j) {
      const int row = arow0 + wr * 64 + m * 16 + g4 + j;
      float v0 = acc[m][0][j] + bi0, v1 = acc[m][1][j] + bi1;
      u16 h0 = f2bf(v0), h1 = f2bf(v1);
      ch[(size_t)row * KDIM + colb] = h0;
      ch[(size_t)row * KDIM + colb + 16] = h1;
      if constexpr (SPLITOUT) {
        cl[(size_t)row * KDIM + colb] = f2bf(v0 - bf2f(h0));
        cl[(size_t)row * KDIM + colb + 16] = f2bf(v1 - bf2f(h1));
      }
    }
  }
}

// ---------------------------------------------------------------------------
// Quantize bf16-hi -> fp8 e4m3, frag-pair-permuted layout (R13-proven).
// grid.y selects (fh->fq) or (gh->gq) -- merged dispatch.
// ---------------------------------------------------------------------------
__global__ __launch_bounds__(256) void quant_kernel(
    const u16* __restrict__ src0, u8* __restrict__ dst0,
    const u16* __restrict__ src1, u8* __restrict__ dst1)
{
  const u16* src = blockIdx.y ? src1 : src0;
  u8* dst = blockIdx.y ? dst1 : dst0;
  const int id = blockIdx.x * 256 + threadIdx.x;   // one 16B cell
  const int row = id >> 6, mtc = id & 63;
  const int mt = mtc >> 3, c = mtc & 7;
  const int k0 = mt * 128 + (c >> 2) * 64 + (c & 3) * 8;
  const u16* s0 = src + (size_t)row * KDIM + k0;
  u8x16 o;
  #pragma unroll
  for (int j = 0; j < 8; ++j) o[j] = f2fp8(bf2f(s0[j]));
  #pragma unroll
  for (int j = 0; j < 8; ++j) o[8 + j] = f2fp8(bf2f(s0[32 + j]));
  *(u8x16*)(dst + (size_t)id * 16) = o;
}

// ---------------------------------------------------------------------------
// Scores sweep R16 = R14 verbatim (best measured: 247us, FETCH 45MB,
// conflicts 0) with ONE change: adjacency is read RAW (int32) in the
// epilogue's batched phase A -- 2 coalesced values per thread per row-chunk
// -- eliminating the separate adjpack dispatch (268MB standalone stream)
// by overlapping that stream with the MFMA phases.
// ---------------------------------------------------------------------------
__global__ __launch_bounds__(512, 2) void scores_kernel(
    const u8* __restrict__ fq, const u8* __restrict__ gq,
    const int* __restrict__ adj, uint32_t* __restrict__ cand,
    int* __restrict__ cnts, int* rowmax)
{
  extern __shared__ char smem[];
  constexpr int NT = 64;                 // 8 key-tiles x 8 megatiles (BK=128)

  const int tid = threadIdx.x, w = tid >> 6, lane = tid & 63;
  const int wr = w >> 2, wc = w & 3;
  const int l15 = lane & 15, g4 = (lane >> 4) << 2, hi4 = lane >> 4;

  // R14 mapping: XCD hosts 8 slabs (128 rows each) x 8 siblings
  const int xcd = blockIdx.x & 7, idx = blockIdx.x >> 3;
  const int slab = xcd * 8 + (idx & 7);
  const int sub  = idx >> 3;             // sibling 0..7 -> key-tiles {sub+8i}
  const int arow0 = slab * 128;

  int srowi[2], scli[2];
  #pragma unroll
  for (int i = 0; i < 2; ++i) {
    const int d = w * 128 + i * 64 + lane;
    srowi[i] = d >> 3;
    scli[i]  = (d & 7) ^ ((d >> 3) & 7);
  }
  const int sdw = w * 2048;

  auto stageA = [&](int T) {
    char* dbase = smem + (T & 1) * 32768 + sdw;
    #pragma unroll
    for (int i = 0; i < 2; ++i)
      glds16(fq + (size_t)(arow0 + srowi[i]) * KDIM + (T & 7) * 128 + scli[i] * 16,
             dbase + i * 1024);
  };
  auto stageB = [&](int T) {
    char* dbase = smem + (T & 1) * 32768 + 16384 + sdw;
    const size_t kb = (size_t)(sub + 8 * (T >> 3)) * 128;
    #pragma unroll
    for (int i = 0; i < 2; ++i)
      glds16(gq + (kb + srowi[i]) * KDIM + (T & 7) * 128 + scli[i] * 16,
             dbase + i * 1024);
  };

  const int kxp0 = ((hi4    ) ^ (l15 & 7)) * 16;
  const int kxp1 = ((hi4 + 4) ^ (l15 & 7)) * 16;
  const int abase = (wr * 64 + l15) * 128;
  const int bbase = 16384 + (wc * 32 + l15) * 128;

  f32x4 acc[4][2];
  #pragma unroll
  for (int m = 0; m < 4; ++m) {
    acc[m][0] = f32x4{0.f, 0.f, 0.f, 0.f};
    acc[m][1] = f32x4{0.f, 0.f, 0.f, 0.f};
  }

  const unsigned long long lmask = (1ull << lane) - 1ull;
  const unsigned long long gm = 0xFFFFull << (lane & 48);

  stageA(0); stageB(0);
  stageA(1); stageB(1);

  i64x2 a[4][2], b[2][2];

  for (int T = 0; T < NT; ++T) {
    if (T == NT - 1) asm volatile("s_waitcnt vmcnt(0)" ::: "memory");
    else             asm volatile("s_waitcnt vmcnt(4)" ::: "memory");
    __builtin_amdgcn_s_barrier();

    const char* sb = smem + (T & 1) * 32768;
    #pragma unroll
    for (int m = 0; m < 4; ++m) {
      a[m][0] = *(const i64x2*)(sb + abase + m * 2048 + kxp0);
      a[m][1] = *(const i64x2*)(sb + abase + m * 2048 + kxp1);
    }
    #pragma unroll
    for (int n = 0; n < 2; ++n) {
      b[n][0] = *(const i64x2*)(sb + bbase + n * 2048 + kxp0);
      b[n][1] = *(const i64x2*)(sb + bbase + n * 2048 + kxp1);
    }
    __builtin_amdgcn_s_setprio(1);
    #pragma unroll
    for (int kp = 0; kp < 2; ++kp)
      #pragma unroll
      for (int kh = 0; kh < 2; ++kh)
        #pragma unroll
        for (int m = 0; m < 4; ++m)
          #pragma unroll
          for (int n = 0; n < 2; ++n)
            acc[m][n] = mfma8(a[m][kp][kh], b[n][kp][kh], acc[m][n]);
    __builtin_amdgcn_s_setprio(0);
    asm volatile("s_waitcnt lgkmcnt(0)" ::: "memory");
    __builtin_amdgcn_s_barrier();

    if (T + 2 < NT) { stageA(T + 2); stageB(T + 2); }

    // ===== key-tile epilogue (every 8 megatiles), latency-overlapped =====
    if ((T & 7) == 7) {
      const int kt = T >> 3;
      const int kcol0 = (sub + 8 * kt) * 128;
      const int keyb = kcol0 + wc * 32 + l15;
      #pragma unroll
      for (int mc = 0; mc < 2; ++mc) {
        // -- phase A: batch-prefetch raw adjacency (2 coalesced ints) + rowmax
        int AV0[2][4], AV1[2][4]; float RX[2][4]; int ROW[2][4];
        #pragma unroll
        for (int mm = 0; mm < 2; ++mm)
          #pragma unroll
          for (int j = 0; j < 4; ++j) {
            const int m = mc * 2 + mm;
            const int row = arow0 + wr * 64 + m * 16 + g4 + j;
            ROW[mm][j] = row;
            const int* ap = adj + (size_t)row * NROWS + keyb;
            AV0[mm][j] = ap[0];
            AV1[mm][j] = ap[16];
            RX[mm][j] = __int_as_float(rowmax[row]);   // stale-tolerant
          }
        // -- phase B: mask/reduce; fire atomicMax; issue atomicAdds
        float SV[2][4][2]; float TH[2][4]; int BS[2][4];
        #pragma unroll
        for (int mm = 0; mm < 2; ++mm)
          #pragma unroll
          for (int j = 0; j < 4; ++j) {
            const int m = mc * 2 + mm;
            float rm = NEGBIG;
            #pragma unroll
            for (int n = 0; n < 2; ++n) {
              float v = fmaxf(acc[m][n][j], 0.f);
              float s = ((n ? AV1[mm][j] : AV0[mm][j]) > 0) ? v : NEGBIG;
              SV[mm][j][n] = s;
              rm = fmaxf(rm, s);
            }
            rm = fmaxf(rm, __shfl_xor(rm, 1));
            rm = fmaxf(rm, __shfl_xor(rm, 2));
            rm = fmaxf(rm, __shfl_xor(rm, 4));
            rm = fmaxf(rm, __shfl_xor(rm, 8));
            const float mr = fmaxf(rm, RX[mm][j]);
            if (l15 == 0 && rm > RX[mm][j])
              atomicMax(rowmax + ROW[mm][j], __float_as_int(rm));
            TH[mm][j] = mr - EMIT_THR;
            int tot = 0;
            #pragma unroll
            for (int n = 0; n < 2; ++n)
              tot += __popcll(__ballot(SV[mm][j][n] > TH[mm][j]) & gm);
            BS[mm][j] = 0;
            if (l15 == 0 && tot > 0)
              BS[mm][j] = atomicAdd(cnts + ROW[mm][j], tot);
          }
        // -- phase C: re-ballot, place, store
        #pragma unroll
        for (int mm = 0; mm < 2; ++mm)
          #pragma unroll
          for (int j = 0; j < 4; ++j) {
            int base = __shfl(BS[mm][j], lane & 48);
            int pref = 0;
            #pragma unroll
            for (int n = 0; n < 2; ++n) {
              unsigned long long mk = __ballot(SV[mm][j][n] > TH[mm][j]);
              const int p = base + pref + __popcll(mk & gm & lmask);
              if ((SV[mm][j][n] > TH[mm][j]) && p < CAP)
                cand[(size_t)ROW[mm][j] * CAP + p] =
                    ((uint32_t)f2bf(SV[mm][j][n]) << 16) | (uint32_t)(keyb + n * 16);
              pref += __popcll(mk & gm);
            }
          }
      }
      #pragma unroll
      for (int m = 0; m < 4; ++m) {
        acc[m][0] = f32x4{0.f, 0.f, 0.f, 0.f};
        acc[m][1] = f32x4{0.f, 0.f, 0.f, 0.f};
      }
    }
  }
}

// ---------------------------------------------------------------------------
// Finalize: survivors (within SURV_THR of approx max) rescored exactly in
// fp32 from (fh+fl, gh+gl); tail stays approx in the denominator only.
// ---------------------------------------------------------------------------
__global__ __launch_bounds__(256) void finalize_kernel(
    const uint32_t* __restrict__ cand, const int* __restrict__ cnts,
    const u16* __restrict__ fh, const u16* __restrict__ fl,
    const u16* __restrict__ gh, const u16* __restrict__ gl,
    const u16* __restrict__ vh, float* __restrict__ out)
{
  const int row = blockIdx.x, tid = threadIdx.x, wv = tid >> 6, lane = tid & 63;
  __shared__ float sS[CAP];
  __shared__ int sK[CAP];
  __shared__ float sF[KDIM];
  __shared__ float sEx[MAXS];
  __shared__ int sKs[MAXS];
  __shared__ float red[4];
  __shared__ int nsig;
  int cnt = cnts[row]; cnt = cnt < CAP ? cnt : CAP;
  const int col = tid * 4;
  if (cnt <= 0) {
    f32x4 z = {0.f, 0.f, 0.f, 0.f};
    *(f32x4*)(out + (size_t)row * KDIM + col) = z;
    return;
  }
  if (tid == 0) nsig = 0;
  {
    us4 h = *(const us4*)(fh + (size_t)row * KDIM + col);
    us4 l = *(const us4*)(fl + (size_t)row * KDIM + col);
    #pragma unroll
    for (int j = 0; j < 4; ++j) sF[col + j] = bf2f(h[j]) + bf2f(l[j]);
  }
  for (int i = tid; i < cnt; i += 256) {
    uint32_t pk = cand[(size_t)row * CAP + i];
    sS[i] = bf2f((u16)(pk >> 16));
    sK[i] = (int)(pk & 0xFFFFu);
  }
  __syncthreads();
  float lm = NEGBIG;
  for (int i = tid; i < cnt; i += 256) lm = fmaxf(lm, sS[i]);
  #pragma unroll
  for (int d = 1; d < 64; d <<= 1) lm = fmaxf(lm, __shfl_xor(lm, d));
  if ((tid & 63) == 0) red[tid >> 6] = lm;
  __syncthreads();
  const float am = fmaxf(fmaxf(red[0], red[1]), fmaxf(red[2], red[3]));
  __syncthreads();
  for (int i = tid; i < cnt; i += 256) {
    if (sS[i] > am - SURV_THR) {
      int p = atomicAdd(&nsig, 1);
      if (p < MAXS) { sKs[p] = sK[i]; sS[i] = NEGBIG; }
    }
  }
  __syncthreads();
  const int ns = nsig < MAXS ? nsig : MAXS;
  for (int si = wv; si < ns; si += 4) {
    const int key = sKs[si];
    const u16* grh = gh + (size_t)key * KDIM + lane * 16;
    const u16* grl = gl + (size_t)key * KDIM + lane * 16;
    float d = 0.f;
    #pragma unroll
    for (int u = 0; u < 4; ++u) {
      us4 h = *(const us4*)(grh + u * 4);
      us4 l = *(const us4*)(grl + u * 4);
      #pragma unroll
      for (int j = 0; j < 4; ++j)
        d += (bf2f(h[j]) + bf2f(l[j])) * sF[lane * 16 + u * 4 + j];
    }
    #pragma unroll
    for (int dd = 1; dd < 64; dd <<= 1) d += __shfl_xor(d, dd);
    if (lane == 0) sEx[si] = fmaxf(d, 0.f);
  }
  __syncthreads();
  float em = NEGBIG;
  for (int i = tid; i < ns; i += 256) em = fmaxf(em, sEx[i]);
  #pragma unroll
  for (int d = 1; d < 64; d <<= 1) em = fmaxf(em, __shfl_xor(em, d));
  if ((tid & 63) == 0) red[tid >> 6] = em;
  __syncthreads();
  const float m = fmaxf(fmaxf(red[0], red[1]), fmaxf(red[2], red[3]));
  __syncthreads();
  float ls = 0.f;
  for (int i = tid; i < cnt; i += 256) {
    float s = sS[i];
    if (s > NEGBIG * 0.5f) ls += __expf(s - m);
  }
  for (int i = tid; i < ns; i += 256) ls += __expf(sEx[i] - m);
  #pragma unroll
  for (int d = 1; d < 64; d <<= 1) ls += __shfl_xor(ls, d);
  if ((tid & 63) == 0) red[tid >> 6] = ls;
  __syncthreads();
  const float inv = 1.f / (red[0] + red[1] + red[2] + red[3]);
  float a0 = 0.f, a1 = 0.f, a2 = 0.f, a3 = 0.f;
  const u16* vbase = vh + col;
  for (int i = 0; i < ns; ++i) {
    const float wt = __expf(sEx[i] - m) * inv;
    us4 vv = *(const us4*)(vbase + (size_t)sKs[i] * KDIM);
    a0 += wt * bf2f(vv[0]); a1 += wt * bf2f(vv[1]);
    a2 += wt * bf2f(vv[2]); a3 += wt * bf2f(vv[3]);
  }
  f32x4 o = {a0, a1, a2, a3};
  *(f32x4*)(out + (size_t)row * KDIM + col) = o;
}

// ---------------------------------------------------------------------------
// Transpose + hi/lo split of a [K][N] fp32 weight into [N][K] bf16 pair.
// grid.z selects which of the 3 weights -- merged dispatch.
// ---------------------------------------------------------------------------
__global__ __launch_bounds__(256) void wsplit_kernel(
    const float* __restrict__ W0, u16* th0, u16* tl0,
    const float* __restrict__ W1, u16* th1, u16* tl1,
    const float* __restrict__ W2, u16* th2, u16* tl2)
{
  const float* W = blockIdx.z == 0 ? W0 : (blockIdx.z == 1 ? W1 : W2);
  u16* th = blockIdx.z == 0 ? th0 : (blockIdx.z == 1 ? th1 : th2);
  u16* tl = blockIdx.z == 0 ? tl0 : (blockIdx.z == 1 ? tl1 : tl2);
  __shared__ float tile[32][33];
  const int bx = blockIdx.x, by = blockIdx.y;
  const int tx = threadIdx.x & 31, ty = threadIdx.x >> 5;
  #pragma unroll
  for (int i = 0; i < 4; ++i) {
    int ky = ty + i * 8;
    tile[ky][tx] = W[(size_t)(by * 32 + ky) * KDIM + bx * 32 + tx];
  }
  __syncthreads();
  #pragma unroll
  for (int i = 0; i < 4; ++i) {
    int ny = ty + i * 8;
    float v = tile[tx][ny];
    u16 h = f2bf(v);
    th[(size_t)(bx * 32 + ny) * KDIM + by * 32 + tx] = h;
    tl[(size_t)(bx * 32 + ny) * KDIM + by * 32 + tx] = f2bf(v - bf2f(h));
  }
}

__global__ __launch_bounds__(256) void xsplit_kernel(
    const float* __restrict__ x, u16* __restrict__ xh, u16* __restrict__ xl)
{
  size_t i = ((size_t)blockIdx.x * 256 + threadIdx.x) * 4;
  f32x4 v = *(const f32x4*)(x + i);
  us4 h, l;
  #pragma unroll
  for (int j = 0; j < 4; ++j) {
    h[j] = f2bf(v[j]);
    l[j] = f2bf(v[j] - bf2f(h[j]));
  }
  *(us4*)(xh + i) = h;
  *(us4*)(xl + i) = l;
}

__global__ void ws_report(float* out, size_t n, float v) {
  for (size_t i = (size_t)blockIdx.x * blockDim.x + threadIdx.x; i < n;
       i += (size_t)gridDim.x * blockDim.x) out[i] = v;
}

extern "C" void kernel_launch(void* const* d_in, const int* in_sizes, int n_in,
                              void* d_out, int out_size, void* d_ws, size_t ws_size,
                              hipStream_t stream) {
  (void)in_sizes; (void)n_in;
  const float* x   = (const float*)d_in[0];
  const int*   adj = (const int*)d_in[1];
  const float* Wf  = (const float*)d_in[2];
  const float* bf_ = (const float*)d_in[3];
  const float* Wg  = (const float*)d_in[4];
  const float* bg_ = (const float*)d_in[5];
  const float* W   = (const float*)d_in[6];
  const float* bW_ = (const float*)d_in[7];

  char* p = (char*)d_ws;
  const size_t ND2 = (size_t)NROWS * KDIM * 2;
  const size_t ND1 = (size_t)NROWS * KDIM;
  const size_t W2  = (size_t)KDIM * KDIM * 2;
  u16* xh = (u16*)p;  p += ND2;
  u16* xl = (u16*)p;  p += ND2;
  u16* fh = (u16*)p;  p += ND2;
  u16* fl = (u16*)p;  p += ND2;
  u16* gh = (u16*)p;  p += ND2;
  u16* gl = (u16*)p;  p += ND2;
  u16* vh = (u16*)p;  p += ND2;
  u16* wfh = (u16*)p; p += W2;
  u16* wfl = (u16*)p; p += W2;
  u16* wgh = (u16*)p; p += W2;
  u16* wgl = (u16*)p; p += W2;
  u16* wh  = (u16*)p; p += W2;
  u16* wl  = (u16*)p; p += W2;
  u8* fq = (u8*)p; p += ND1;
  u8* gq = (u8*)p; p += ND1;
  uint32_t* cand = (uint32_t*)p; p += (size_t)NROWS * CAP * 4;
  int* cnts   = (int*)p; p += (size_t)NROWS * 4;
  int* rowmax = (int*)p; p += (size_t)NROWS * 4;
  const size_t need = (size_t)(p - (char*)d_ws);
  if (ws_size < need) {
    ws_report<<<256, 256, 0, stream>>>((float*)d_out, (size_t)out_size, (float)ws_size);
    return;
  }

  auto kf = gemm_kernel<3, true>;
  auto kv = gemm_kernel<1, false>;
  hipFuncSetAttribute((const void*)kf, hipFuncAttributeMaxDynamicSharedMemorySize, 131072);
  hipFuncSetAttribute((const void*)kv, hipFuncAttributeMaxDynamicSharedMemorySize, 65536);
  hipFuncSetAttribute((const void*)scores_kernel, hipFuncAttributeMaxDynamicSharedMemorySize, 65536);

  hipMemsetAsync(cnts, 0, (size_t)NROWS * 8, stream);   // cnts + rowmax (0 == 0.0f)
  wsplit_kernel<<<dim3(32, 32, 3), 256, 0, stream>>>(Wf, wfh, wfl, Wg, wgh, wgl,
                                                     W, wh, wl);
  xsplit_kernel<<<(NROWS * KDIM) / (256 * 4), 256, 0, stream>>>(x, xh, xl);

  // f = x@Wf + bf, g = x@Wg + bg (split-3, hi+lo out), v = x@W + bW (1 pass)
  kf<<<dim3(64, 8), 512, 131072, stream>>>(xh, xl, wfh, wfl, bf_, fh, fl);
  kf<<<dim3(64, 8), 512, 131072, stream>>>(xh, xl, wgh, wgl, bg_, gh, gl);
  kv<<<dim3(64, 8), 512, 65536, stream>>>(xh, xl, wh, wl, bW_, vh, nullptr);
  // fp8 quantize (frag-pair permuted) for the scores sweep -- merged dispatch
  quant_kernel<<<dim3((NROWS * 64) / 256, 2), 256, 0, stream>>>(fh, fq, gh, gq);
  // 2-wg/CU fp8 scores sweep with raw-adj epilogue (adjpack eliminated)
  scores_kernel<<<dim3(512), 512, 65536, stream>>>(fq, gq, adj, cand, cnts, rowmax);
  // exact rescoring of survivors + softmax + v gather
  finalize_kernel<<<NROWS, 256, 0, stream>>>(cand, cnts, fh, fl, gh, gl, vh,
                                             (float*)d_out);
}